// Round 2
// baseline (426.241 us; speedup 1.0000x reference)
//
#include <hip/hip_runtime.h>
#include <math.h>

// HyperbolicParamAdapter: expmap0 -> mobius diag scale -> project -> logmap0
// out_i = p_i * w_i * total, total = s1*s2*pf*s3 where the scalar chain
// depends only on two row reductions: sum(p_i^2) and sum((p_i*w_i)^2).
//   s1 = tanh(0.1*||p||)/(0.1*||p||)            (expmap0: x = s1*p)
//   s2 = tanh(mxn/xn * artanh(0.1*xn))/(0.1*mxn) (mobius: res = s2*mx, mx=s1*(p.w))
//   pf = projection factor, s3 = logmap0 factor
// One wave (64 lanes) per row of 512 floats: 2x float4 per lane, butterfly
// shuffle reduction, redundant per-lane scalar math, one coalesced write.
// R1 bug: total was missing the s1 factor (absmax 7.906 = (s3-1)*max|p| exactly).

#define SQRT_C   0.1f
#define MIN_NORM 1e-5f
#define CLAMP_EPS 1e-5f

__global__ __launch_bounds__(256) void hyper_adapter_kernel(
    const float* __restrict__ params,
    const float* __restrict__ weights,
    float* __restrict__ out,
    int n_rows)
{
    const int lane = threadIdx.x & 63;
    const int wave = threadIdx.x >> 6;                 // 0..3 waves per block
    const int row  = blockIdx.x * 4 + wave;
    if (row >= n_rows) return;

    const float4* prow = (const float4*)(params + (size_t)row * 512);
    const float4* wv   = (const float4*)weights;
    float4*       orow = (float4*)(out + (size_t)row * 512);

    // lane i holds row elements [4i..4i+3] and [256+4i..256+4i+3] (coalesced)
    float4 p0 = prow[lane];
    float4 p1 = prow[64 + lane];
    float4 w0 = wv[lane];
    float4 w1 = wv[64 + lane];

    float4 m0 = make_float4(p0.x * w0.x, p0.y * w0.y, p0.z * w0.z, p0.w * w0.w);
    float4 m1 = make_float4(p1.x * w1.x, p1.y * w1.y, p1.z * w1.z, p1.w * w1.w);

    float sp  = p0.x * p0.x + p0.y * p0.y + p0.z * p0.z + p0.w * p0.w
              + p1.x * p1.x + p1.y * p1.y + p1.z * p1.z + p1.w * p1.w;
    float spw = m0.x * m0.x + m0.y * m0.y + m0.z * m0.z + m0.w * m0.w
              + m1.x * m1.x + m1.y * m1.y + m1.z * m1.z + m1.w * m1.w;

    // 64-lane butterfly reduction (all lanes end with the full sums)
    #pragma unroll
    for (int off = 32; off > 0; off >>= 1) {
        sp  += __shfl_xor(sp,  off, 64);
        spw += __shfl_xor(spw, off, 64);
    }

    // ---- scalar chain (redundant across lanes) ----
    float pn     = sqrtf(sp);                       // ||p|| (unclamped)
    float u_norm = fmaxf(pn, MIN_NORM);             // _norm(params)
    float a      = SQRT_C * u_norm;
    float s1     = tanhf(a) / a;                    // x = s1 * p

    float x_norm  = fmaxf(s1 * pn, MIN_NORM);       // _norm(x) = max(||x||, 1e-5)
    float mx_norm = s1 * sqrtf(spw);                // ||mx|| (NOT clamped, per ref)

    float z1 = fminf(fmaxf(SQRT_C * x_norm, -1.0f + CLAMP_EPS), 1.0f - CLAMP_EPS);
    float th = tanhf(mx_norm / x_norm * atanhf(z1));
    float s2 = th / (mx_norm * SQRT_C);             // res = s2 * mx = s2 * s1 * (p.w)

    float res_norm = th / SQRT_C;                   // ||res|| = th/sqrt(c), th >= 0
    // _project
    float rn      = fmaxf(res_norm, MIN_NORM);
    const float maxnorm = (1.0f - 0.001f) / SQRT_C; // 9.99
    float pf      = (rn > maxnorm) ? (maxnorm / rn) : 1.0f;

    // logmap0
    float y_norm = fmaxf(res_norm * pf, MIN_NORM);
    float z2 = fminf(fmaxf(SQRT_C * y_norm, -1.0f + CLAMP_EPS), 1.0f - CLAMP_EPS);
    float s3 = atanhf(z2) / (y_norm * SQRT_C);

    float total = s1 * s2 * pf * s3;                // applied to m (= p*w)

    orow[lane]      = make_float4(m0.x * total, m0.y * total, m0.z * total, m0.w * total);
    orow[64 + lane] = make_float4(m1.x * total, m1.y * total, m1.z * total, m1.w * total);
}

extern "C" void kernel_launch(void* const* d_in, const int* in_sizes, int n_in,
                              void* d_out, int out_size, void* d_ws, size_t ws_size,
                              hipStream_t stream) {
    const float* params  = (const float*)d_in[0];
    const float* weights = (const float*)d_in[1];
    float* out = (float*)d_out;

    const int n_rows = in_sizes[0] / 512;           // 131072 rows of d=512
    const int blocks = (n_rows + 3) / 4;            // 4 rows (waves) per block

    hyper_adapter_kernel<<<blocks, 256, 0, stream>>>(params, weights, out, n_rows);
}